// Round 1
// 168.806 us; speedup vs baseline: 1.0235x; 1.0235x over previous
//
#include <hip/hip_runtime.h>
#include <math.h>

typedef _Float16 half_t;
typedef _Float16 half8  __attribute__((ext_vector_type(8)));
typedef _Float16 half4v __attribute__((ext_vector_type(4)));
typedef float    floatx4 __attribute__((ext_vector_type(4)));

#define LOG2E 1.44269504088896f

static __device__ __forceinline__ floatx4 mfma16(half8 a, half8 b, floatx4 c) {
    return __builtin_amdgcn_mfma_f32_16x16x32_f16(a, b, c, 0, 0, 0);
}
static __device__ __forceinline__ floatx4 mfma16x16(half4v a, half4v b, floatx4 c) {
    return __builtin_amdgcn_mfma_f32_16x16x16f16(a, b, c, 0, 0, 0);
}

// ---------------------------------------------------------------------------
// prep (256 thr): z=0 cache_k -> Kc[bh][j][d] fp16 + out_k shift fp32
//                 z=1 cache_v -> VcT[bh][d][j] fp16 + out_v shift fp32
//                 z=2 weight transposes + embc build. All float4 loads.
// ---------------------------------------------------------------------------
__global__ __launch_bounds__(256) void prep(const float* __restrict__ cache_k,
                                            const float* __restrict__ cache_v,
                                            const float* __restrict__ Wq,
                                            const float* __restrict__ Wk,
                                            const float* __restrict__ Wv,
                                            const float* __restrict__ Wo,
                                            const float* __restrict__ emb_t,
                                            const float* __restrict__ emb_f,
                                            half_t* __restrict__ Kc,
                                            half_t* __restrict__ VcT,
                                            float* __restrict__ out_k,
                                            float* __restrict__ out_v,
                                            half_t* __restrict__ WqT,
                                            half_t* __restrict__ WkvT,
                                            half_t* __restrict__ WoT,
                                            half_t* __restrict__ embc)
{
    const int tid = threadIdx.x;
    const int z = blockIdx.z;
    __shared__ float t[64][65];
    if (z == 0) {
        const int bh = blockIdx.y, j0 = blockIdx.x * 64;
        const bool shift = (j0 >= 512);
        #pragma unroll
        for (int i2 = 0; i2 < 4; i2++) {
            int idx = i2 * 256 + tid;
            int d = idx >> 4, j4 = (idx & 15) * 4;
            float4 vv = *(const float4*)&cache_k[((size_t)bh * 64 + d) * 1536 + j0 + j4];
            *(float4*)&t[d][j4] = vv;
            if (shift) *(float4*)&out_k[((size_t)bh * 64 + d) * 1536 + j0 - 512 + j4] = vv;
        }
        __syncthreads();
        #pragma unroll
        for (int i2 = 0; i2 < 2; i2++) {
            int idx = i2 * 256 + tid;
            int j = idx >> 3, db = (idx & 7) * 8;
            half8 o;
            #pragma unroll
            for (int u = 0; u < 8; u++) o[u] = (half_t)t[db + u][j];
            *(half8*)&Kc[((size_t)bh * 1536 + j0 + j) * 64 + db] = o;
        }
    } else if (z == 1) {
        const int bh = blockIdx.y, j0 = blockIdx.x * 64;
        const bool shift = (j0 >= 512);
        #pragma unroll
        for (int i2 = 0; i2 < 4; i2++) {
            int idx = i2 * 256 + tid;
            int j = idx >> 4, d4 = (idx & 15) * 4;
            float4 vv = *(const float4*)&cache_v[((size_t)bh * 1536 + j0 + j) * 64 + d4];
            *(float4*)&t[j][d4] = vv;
            if (shift) *(float4*)&out_v[((size_t)bh * 1536 + j0 + j - 512) * 64 + d4] = vv;
        }
        __syncthreads();
        #pragma unroll
        for (int i2 = 0; i2 < 2; i2++) {
            int idx = i2 * 256 + tid;
            int d = idx >> 3, jb = (idx & 7) * 8;
            half8 o;
            #pragma unroll
            for (int u = 0; u < 8; u++) o[u] = (half_t)t[jb + u][d];
            *(half8*)&VcT[((size_t)bh * 64 + d) * 1536 + j0 + jb] = o;
        }
    } else {
        const int id = blockIdx.y * 24 + blockIdx.x;
        const float* src; half_t* dst; int Ncols, n0, k0;
        if (id < 256)      { src = Wq; dst = WqT; Ncols = 1024; n0 = (id & 15) * 64; k0 = (id >> 4) * 64; }
        else if (id < 320) { int q2 = id - 256; src = Wk; dst = WkvT; Ncols = 256; n0 = (q2 & 3) * 64; k0 = (q2 >> 2) * 64; }
        else if (id < 384) { int q2 = id - 320; src = Wv; dst = WkvT + 256 * 1024; Ncols = 256; n0 = (q2 & 3) * 64; k0 = (q2 >> 2) * 64; }
        else if (id < 640) { int q2 = id - 384; src = Wo; dst = WoT; Ncols = 1024; n0 = (q2 & 15) * 64; k0 = (q2 >> 4) * 64; }
        else if (id < 720) {
            int idx = (id - 640) * 256 + tid;
            int row = idx >> 6, col = idx & 63;
            float val = 0.f;
            if (row < 255) val = emb_t[row * 64 + col];
            else if (row >= 256 && row < 271) val = emb_f[(row - 256) * 64 + col];
            embc[idx] = (half_t)val;
            return;
        } else return;
        #pragma unroll
        for (int i2 = 0; i2 < 4; i2++) {
            int idx = i2 * 256 + tid;
            int r = idx >> 4, c4 = (idx & 15) * 4;
            *(float4*)&t[r][c4] = *(const float4*)&src[(size_t)(k0 + r) * Ncols + n0 + c4];
        }
        __syncthreads();
        #pragma unroll
        for (int i2 = 0; i2 < 2; i2++) {
            int idx = i2 * 256 + tid;
            int n = idx >> 3, kb = (idx & 7) * 8;
            half8 o;
            #pragma unroll
            for (int u = 0; u < 8; u++) o[u] = (half_t)t[kb + u][n];
            *(half8*)&dst[(size_t)(n0 + n) * 1024 + k0 + kb] = o;
        }
    }
}

// ---------------------------------------------------------------------------
// proj (512 thr, 8 waves, K-split): two 4-wave groups each GEMM half of K
// (BK=64 x 8 iters, double-buffered, register prefetch), fp32 LDS merge.
// phase 0: blocks 0..255 q-proj (fp16, x0.125*log2e), 256..383 k/v-proj
// (LDS-transpose epilogue). phase 1: out-proj (fp32 out).
// ---------------------------------------------------------------------------
__global__ __launch_bounds__(512) void proj(int phase,
                                            const float* __restrict__ qin,
                                            const float* __restrict__ kin,
                                            const float* __restrict__ vin,
                                            const half_t* __restrict__ AO,
                                            const half_t* __restrict__ WqT,
                                            const half_t* __restrict__ WkvT,
                                            const half_t* __restrict__ WoT,
                                            half_t* __restrict__ qs_h,
                                            half_t* __restrict__ kp_h,
                                            half_t* __restrict__ vpT,
                                            float* __restrict__ out,
                                            float* __restrict__ out_k,
                                            float* __restrict__ out_v)
{
    __shared__ __align__(16) half_t As[2][2][64 * 72];
    __shared__ __align__(16) half_t Bs[2][2][64 * 72];
    const int id = blockIdx.x;
    int task, m0, n0;
    const float* Af = nullptr; const half_t* Ah = nullptr; const half_t* Bt;
    if (phase == 1)      { task = 2; m0 = (id >> 4) * 64; n0 = (id & 15) * 64; Ah = AO; Bt = WoT; }
    else if (id < 256)   { task = 0; m0 = (id >> 4) * 64; n0 = (id & 15) * 64; Af = qin; Bt = WqT; }
    else { task = 1; int t = id - 256; m0 = (t >> 3) * 64; n0 = (t & 7) * 64;
           Af = (n0 < 256) ? kin : vin; Bt = WkvT; }

    const int tid = threadIdx.x;
    const int kh = tid >> 8, t8 = tid & 255;
    const int w4 = (tid >> 6) & 3, l = tid & 63;
    const int quad = l >> 4, lr = l & 15, wm = w4 >> 1, wn = w4 & 1;
    const int arow = t8 >> 2, acol = (t8 & 3) * 16;
    const int kbase = kh * 512;

    {   // stage tile 0
        int kk = kbase;
        if (Af) {
            float4 f0 = *(const float4*)&Af[(size_t)(m0 + arow) * 1024 + kk + acol];
            float4 f1 = *(const float4*)&Af[(size_t)(m0 + arow) * 1024 + kk + acol + 4];
            float4 f2 = *(const float4*)&Af[(size_t)(m0 + arow) * 1024 + kk + acol + 8];
            float4 f3 = *(const float4*)&Af[(size_t)(m0 + arow) * 1024 + kk + acol + 12];
            half8 h0, h1;
            h0[0]=(half_t)f0.x; h0[1]=(half_t)f0.y; h0[2]=(half_t)f0.z; h0[3]=(half_t)f0.w;
            h0[4]=(half_t)f1.x; h0[5]=(half_t)f1.y; h0[6]=(half_t)f1.z; h0[7]=(half_t)f1.w;
            h1[0]=(half_t)f2.x; h1[1]=(half_t)f2.y; h1[2]=(half_t)f2.z; h1[3]=(half_t)f2.w;
            h1[4]=(half_t)f3.x; h1[5]=(half_t)f3.y; h1[6]=(half_t)f3.z; h1[7]=(half_t)f3.w;
            *(half8*)&As[kh][0][arow * 72 + acol] = h0;
            *(half8*)&As[kh][0][arow * 72 + acol + 8] = h1;
        } else {
            *(half8*)&As[kh][0][arow * 72 + acol]     = *(const half8*)&Ah[(size_t)(m0 + arow) * 1024 + kk + acol];
            *(half8*)&As[kh][0][arow * 72 + acol + 8] = *(const half8*)&Ah[(size_t)(m0 + arow) * 1024 + kk + acol + 8];
        }
        *(half8*)&Bs[kh][0][arow * 72 + acol]     = *(const half8*)&Bt[(size_t)(n0 + arow) * 1024 + kk + acol];
        *(half8*)&Bs[kh][0][arow * 72 + acol + 8] = *(const half8*)&Bt[(size_t)(n0 + arow) * 1024 + kk + acol + 8];
    }
    __syncthreads();

    floatx4 zero = {0.f, 0.f, 0.f, 0.f};
    floatx4 acc[2][2];
    acc[0][0] = zero; acc[0][1] = zero; acc[1][0] = zero; acc[1][1] = zero;

    float4 pf0, pf1, pf2, pf3; half8 ph0, ph1, pb0, pb1;
    for (int it = 0; it < 8; ++it) {
        if (it < 7) {
            int kk = kbase + (it + 1) * 64;
            if (Af) {
                pf0 = *(const float4*)&Af[(size_t)(m0 + arow) * 1024 + kk + acol];
                pf1 = *(const float4*)&Af[(size_t)(m0 + arow) * 1024 + kk + acol + 4];
                pf2 = *(const float4*)&Af[(size_t)(m0 + arow) * 1024 + kk + acol + 8];
                pf3 = *(const float4*)&Af[(size_t)(m0 + arow) * 1024 + kk + acol + 12];
            } else {
                ph0 = *(const half8*)&Ah[(size_t)(m0 + arow) * 1024 + kk + acol];
                ph1 = *(const half8*)&Ah[(size_t)(m0 + arow) * 1024 + kk + acol + 8];
            }
            pb0 = *(const half8*)&Bt[(size_t)(n0 + arow) * 1024 + kk + acol];
            pb1 = *(const half8*)&Bt[(size_t)(n0 + arow) * 1024 + kk + acol + 8];
        }
        const half_t* Ab = &As[kh][it & 1][0];
        const half_t* Bb = &Bs[kh][it & 1][0];
        #pragma unroll
        for (int ks = 0; ks < 2; ++ks) {
            half8 a0 = *(const half8*)&Ab[(wm * 32 + lr) * 72 + ks * 32 + quad * 8];
            half8 a1 = *(const half8*)&Ab[(wm * 32 + 16 + lr) * 72 + ks * 32 + quad * 8];
            half8 b0 = *(const half8*)&Bb[(wn * 32 + lr) * 72 + ks * 32 + quad * 8];
            half8 b1 = *(const half8*)&Bb[(wn * 32 + 16 + lr) * 72 + ks * 32 + quad * 8];
            acc[0][0] = mfma16(a0, b0, acc[0][0]);
            acc[0][1] = mfma16(a0, b1, acc[0][1]);
            acc[1][0] = mfma16(a1, b0, acc[1][0]);
            acc[1][1] = mfma16(a1, b1, acc[1][1]);
        }
        __syncthreads();
        if (it < 7) {
            int buf = (it + 1) & 1;
            if (Af) {
                half8 h0, h1;
                h0[0]=(half_t)pf0.x; h0[1]=(half_t)pf0.y; h0[2]=(half_t)pf0.z; h0[3]=(half_t)pf0.w;
                h0[4]=(half_t)pf1.x; h0[5]=(half_t)pf1.y; h0[6]=(half_t)pf1.z; h0[7]=(half_t)pf1.w;
                h1[0]=(half_t)pf2.x; h1[1]=(half_t)pf2.y; h1[2]=(half_t)pf2.z; h1[3]=(half_t)pf2.w;
                h1[4]=(half_t)pf3.x; h1[5]=(half_t)pf3.y; h1[6]=(half_t)pf3.z; h1[7]=(half_t)pf3.w;
                *(half8*)&As[kh][buf][arow * 72 + acol] = h0;
                *(half8*)&As[kh][buf][arow * 72 + acol + 8] = h1;
            } else {
                *(half8*)&As[kh][buf][arow * 72 + acol] = ph0;
                *(half8*)&As[kh][buf][arow * 72 + acol + 8] = ph1;
            }
            *(half8*)&Bs[kh][buf][arow * 72 + acol] = pb0;
            *(half8*)&Bs[kh][buf][arow * 72 + acol + 8] = pb1;
            __syncthreads();
        }
    }

    // merge K-halves (kh1 -> LDS fp32, kh0 adds)
    float* M = (float*)&Bs[0][0][0];   // 64 x 66 floats
    if (kh == 1) {
        #pragma unroll
        for (int mi = 0; mi < 2; mi++)
            #pragma unroll
            for (int ni = 0; ni < 2; ni++)
                #pragma unroll
                for (int r = 0; r < 4; r++)
                    M[(wm * 32 + mi * 16 + quad * 4 + r) * 66 + wn * 32 + ni * 16 + lr] = acc[mi][ni][r];
    }
    __syncthreads();
    if (kh == 0) {
        #pragma unroll
        for (int mi = 0; mi < 2; mi++)
            #pragma unroll
            for (int ni = 0; ni < 2; ni++)
                #pragma unroll
                for (int r = 0; r < 4; r++)
                    acc[mi][ni][r] += M[(wm * 32 + mi * 16 + quad * 4 + r) * 66 + wn * 32 + ni * 16 + lr];
    }

    if (task == 0) {
        if (kh == 0) {
            #pragma unroll
            for (int mi = 0; mi < 2; mi++)
                #pragma unroll
                for (int ni = 0; ni < 2; ni++)
                    #pragma unroll
                    for (int r = 0; r < 4; r++) {
                        int m = m0 + wm * 32 + mi * 16 + quad * 4 + r;
                        int n = n0 + wn * 32 + ni * 16 + lr;
                        qs_h[(size_t)m * 1024 + n] = (half_t)(acc[mi][ni][r] * (0.125f * LOG2E));
                    }
        }
    } else if (task == 2) {
        if (kh == 0) {
            #pragma unroll
            for (int mi = 0; mi < 2; mi++)
                #pragma unroll
                for (int ni = 0; ni < 2; ni++)
                    #pragma unroll
                    for (int r = 0; r < 4; r++) {
                        int m = m0 + wm * 32 + mi * 16 + quad * 4 + r;
                        int n = n0 + wn * 32 + ni * 16 + lr;
                        out[(size_t)m * 1024 + n] = acc[mi][ni][r];
                    }
        }
    } else {
        float* Ct = (float*)&As[0][0][0];   // 64 x 68 floats (transposed acc)
        if (kh == 0) {
            #pragma unroll
            for (int mi = 0; mi < 2; mi++)
                #pragma unroll
                for (int ni = 0; ni < 2; ni++)
                    #pragma unroll
                    for (int r = 0; r < 4; r++)
                        Ct[(wn * 32 + ni * 16 + lr) * 68 + wm * 32 + mi * 16 + quad * 4 + r] = acc[mi][ni][r];
        }
        __syncthreads();
        if (kh == 0) {
            const int b = m0 >> 9, jm0 = m0 & 511;
            if (n0 < 256) {
                int gg = n0 >> 6;
                {
                    int d = t8 >> 2, jc = (t8 & 3) * 16;
                    float4 vv[4];
                    #pragma unroll
                    for (int u = 0; u < 4; u++) vv[u] = *(float4*)&Ct[d * 68 + jc + u * 4];
                    #pragma unroll
                    for (int t = 0; t < 4; t++)
                        #pragma unroll
                        for (int u = 0; u < 4; u++)
                            *(float4*)&out_k[((size_t)((b * 16 + gg * 4 + t) * 64 + d)) * 1536 + 1024 + jm0 + jc + u * 4] = vv[u];
                }
                {
                    int j = t8 >> 2, dc = (t8 & 3) * 16;
                    half8 o0, o1;
                    #pragma unroll
                    for (int u = 0; u < 8; u++) o0[u] = (half_t)Ct[(dc + u) * 68 + j];
                    #pragma unroll
                    for (int u = 0; u < 8; u++) o1[u] = (half_t)Ct[(dc + 8 + u) * 68 + j];
                    *(half8*)&kp_h[((size_t)(b * 512 + jm0 + j)) * 256 + n0 + dc] = o0;
                    *(half8*)&kp_h[((size_t)(b * 512 + jm0 + j)) * 256 + n0 + dc + 8] = o1;
                }
            } else {
                int gg = (n0 - 256) >> 6;
                {
                    int j = t8 >> 2, dc = (t8 & 3) * 16;
                    float4 vv[4];
                    #pragma unroll
                    for (int u = 0; u < 4; u++) {
                        float4 x;
                        x.x = Ct[(dc + u * 4 + 0) * 68 + j];
                        x.y = Ct[(dc + u * 4 + 1) * 68 + j];
                        x.z = Ct[(dc + u * 4 + 2) * 68 + j];
                        x.w = Ct[(dc + u * 4 + 3) * 68 + j];
                        vv[u] = x;
                    }
                    #pragma unroll
                    for (int t = 0; t < 4; t++)
                        #pragma unroll
                        for (int u = 0; u < 4; u++)
                            *(float4*)&out_v[(((size_t)(b * 16 + gg * 4 + t) * 1536) + 1024 + jm0 + j) * 64 + dc + u * 4] = vv[u];
                }
                {
                    int d = t8 >> 2, jc = (t8 & 3) * 16;
                    half8 o0, o1;
                    #pragma unroll
                    for (int u = 0; u < 8; u++) o0[u] = (half_t)Ct[d * 68 + jc + u];
                    #pragma unroll
                    for (int u = 0; u < 8; u++) o1[u] = (half_t)Ct[d * 68 + jc + 8 + u];
                    *(half8*)&vpT[((size_t)((b * 4 + gg) * 64 + d)) * 512 + jm0 + jc] = o0;
                    *(half8*)&vpT[((size_t)((b * 4 + gg) * 64 + d)) * 512 + jm0 + jc + 8] = o1;
                }
            }
        }
    }
}

// ---------------------------------------------------------------------------
// Flash v5: 512 thr / 8 waves, 32 Q-rows per block, grid (bh=32, it=16)=512
// -> 2 blocks/CU x 8 waves = 16 waves/CU (2x v4). Wave (wq, jh): wq = i-half
// of 16 rows, jh = j-quarter (32 of each 128-j tile).
// LDS XOR-swizzled (16B blocks, row&7) -> conflict-free ds_read_b128/b64,
// no pads (Ks 16KB, Vs 16KB, Qs 4KB, bt 13.4KB = 50.3KB).
// Row sums via MFMA with ones-B operand (no per-lane adds, no shuffles);
// sums land in the same quad*4+r row layout as accO. 4-way jh merge in LDS.
// ---------------------------------------------------------------------------
__global__ __launch_bounds__(512, 4) void flash(const half_t* __restrict__ qs_h,
                                                const half_t* __restrict__ Kc,
                                                const half_t* __restrict__ kp_h,
                                                const half_t* __restrict__ VcT,
                                                const half_t* __restrict__ vpT,
                                                const half_t* __restrict__ embc,
                                                half_t* __restrict__ AO)
{
    __shared__ __align__(16) half_t smem[25152];        // 50304 B
    half_t* Ks = smem;            // [128][64]  swizzled: chunk ^= row&7
    half_t* Vs = smem + 8192;     // [64][128]  (V^T [d][j]) swizzled: chunk ^= d&7
    half_t* Qs = smem + 16384;    // [32][64]   swizzled: chunk ^= row&7
    half_t* bt = smem + 18432;    // [32][210]

    const int bh = blockIdx.x, b = bh >> 4, h = bh & 15, g = h >> 2;
    const int i0 = blockIdx.y * 32;
    const int tid = threadIdx.x, w = tid >> 6, l = tid & 63;
    const int quad = l >> 4, lr = l & 15;
    const int wq = w >> 2, jh = w & 3;

    // stage Q (32 rows x 64), swizzled
    if (tid < 256) {
        int row = tid >> 3, cc = tid & 7;
        *(half8*)&Qs[row * 64 + ((cc ^ (row & 7)) * 8)] =
            *(const half8*)&qs_h[((size_t)(b * 512 + i0 + row)) * 1024 + h * 64 + cc * 8];
    }

    // preload tile-0 K/V into registers (K: 128x64, V^T: 64x128)
    half8 kr[2], vr[2];
    #pragma unroll
    for (int u = 0; u < 2; u++) {
        int row = u * 64 + (tid >> 3);
        kr[u] = *(const half8*)&Kc[((size_t)bh * 1536 + row) * 64 + (tid & 7) * 8];
        int d = u * 32 + (tid >> 4);
        vr[u] = *(const half8*)&VcT[((size_t)bh * 64 + d) * 1536 + (tid & 15) * 8];
    }
    __syncthreads();   // Qs ready

    // Q as B-operand frags (lane n = i = wq*16+lr); swizzled read
    half8 qf0 = *(const half8*)&Qs[(wq * 16 + lr) * 64 + ((quad ^ (lr & 7)) * 8)];
    half8 qf1 = *(const half8*)&Qs[(wq * 16 + lr) * 64 + (((4 + quad) ^ (lr & 7)) * 8)];

    floatx4 zero = {0.f, 0.f, 0.f, 0.f};
    // bias GEMM: bt[i][t-64] = q_i . embc[t], 13 tk-chunks split 4-way by jh
    for (int tk = 4 + jh; tk < 17; tk += 4) {
        floatx4 acc = zero;
        half8 e0 = *(const half8*)&embc[(size_t)(tk * 16 + lr) * 64 + quad * 8];
        half8 e1 = *(const half8*)&embc[(size_t)(tk * 16 + lr) * 64 + 32 + quad * 8];
        acc = mfma16(e0, qf0, acc);        // D[m=t][n=i]
        acc = mfma16(e1, qf1, acc);
        #pragma unroll
        for (int r = 0; r < 4; r++)
            bt[(wq * 16 + lr) * 210 + tk * 16 + quad * 4 + r - 64] = (half_t)acc[r];
    }

    // write tile-0 K/V to LDS (swizzled)
    #pragma unroll
    for (int u = 0; u < 2; u++) {
        int row = u * 64 + (tid >> 3);
        *(half8*)&Ks[row * 64 + (((tid & 7) ^ (row & 7)) * 8)] = kr[u];
        int d = u * 32 + (tid >> 4);
        *(half8*)&Vs[d * 128 + (((tid & 15) ^ (d & 7)) * 8)] = vr[u];
    }
    __syncthreads();   // bt + tile0 ready

    // per-thread constants: this lane owns row i = wq*16 + lr
    const int qtr = (i0 + wq * 16 + lr) >> 3;
    float bfv[4];
    #pragma unroll
    for (int r = 0; r < 4; r++) {
        int f = (lr & 7) - ((quad & 1) * 4 + r) + 7;     // 0..14
        bfv[r] = (float)bt[(wq * 16 + lr) * 210 + 192 + f];
    }

    floatx4 accO[4];
    #pragma unroll
    for (int ni = 0; ni < 4; ni++) accO[ni] = zero;
    floatx4 accS = zero;                  // row sums, rows quad*4+r (ones-B MFMA)
    const half4v vone = {(half_t)1.f, (half_t)1.f, (half_t)1.f, (half_t)1.f};

    for (int jt = 0; jt < 16; ++jt) {
        if (jt < 15) {   // prefetch next tile into registers
            const int j1 = (jt + 1) * 128;
            #pragma unroll
            for (int u = 0; u < 2; u++) {
                int row = u * 64 + (tid >> 3);
                const half_t* ksrc = (j1 < 1536)
                    ? &Kc[((size_t)bh * 1536 + j1 + row) * 64 + (tid & 7) * 8]
                    : &kp_h[((size_t)(b * 512 + j1 - 1536 + row)) * 256 + g * 64 + (tid & 7) * 8];
                kr[u] = *(const half8*)ksrc;
                int d = u * 32 + (tid >> 4);
                const half_t* vsrc = (j1 < 1536)
                    ? &VcT[((size_t)bh * 64 + d) * 1536 + j1 + (tid & 15) * 8]
                    : &vpT[((size_t)(b * 4 + g) * 64 + d) * 512 + (j1 - 1536) + (tid & 15) * 8];
                vr[u] = *(const half8*)vsrc;
            }
        }

        // S^T = K . Q^T : D[m=j][n=i], 2 chunks of 16 j (this wave's quarter)
        floatx4 s[2];
        #pragma unroll
        for (int c = 0; c < 2; c++) {
            int row = jh * 32 + c * 16 + lr;
            half8 kf0 = *(const half8*)&Ks[row * 64 + ((quad ^ (row & 7)) * 8)];
            half8 kf1 = *(const half8*)&Ks[row * 64 + (((4 + quad) ^ (row & 7)) * 8)];
            s[c] = mfma16(kf0, qf0, zero);
            s[c] = mfma16(kf1, qf1, s[c]);
        }
        // bias + exp2 (no max: scores bounded)
        const int ktb = jt * 16 + jh * 4 + (quad >> 1);
        const half_t* btrow = &bt[(wq * 16 + lr) * 210];
        #pragma unroll
        for (int c = 0; c < 2; c++) {
            int toff = 255 + qtr - (ktb + c * 2);
            toff = min(toff, 190);
            float tb = (float)btrow[toff];
            #pragma unroll
            for (int r = 0; r < 4; r++)
                s[c][r] = exp2f(s[c][r] + tb + bfv[r]);
        }
        // P regs -> A-frags (16x16x16: m=lane=i, k=quad*4+r=j) ; PV + row sums
        #pragma unroll
        for (int c = 0; c < 2; c++) {
            half4v pf;
            #pragma unroll
            for (int r = 0; r < 4; r++) pf[r] = (half_t)s[c][r];
            accS = mfma16x16(pf, vone, accS);          // D[m=i][*] = rowsum
            const int bj = jh * 4 + c * 2 + (quad >> 1);
            #pragma unroll
            for (int ni = 0; ni < 4; ni++) {
                int d = ni * 16 + lr;
                half4v vb = *(const half4v*)&Vs[d * 128 + ((bj ^ (lr & 7)) * 8) + (quad & 1) * 4];
                accO[ni] = mfma16x16(pf, vb, accO[ni]);
            }
        }
        __syncthreads();   // all waves done with Ks/Vs
        if (jt < 15) {
            #pragma unroll
            for (int u = 0; u < 2; u++) {
                int row = u * 64 + (tid >> 3);
                *(half8*)&Ks[row * 64 + (((tid & 7) ^ (row & 7)) * 8)] = kr[u];
                int d = u * 32 + (tid >> 4);
                *(half8*)&Vs[d * 128 + (((tid & 15) ^ (d & 7)) * 8)] = vr[u];
            }
            __syncthreads();
        }
    }

    // 4-way jh merge in LDS (reuse Ks/Vs region, all dead now).
    // Partials p = (jh-1)*2 + wq, each 16 rows x 68-stride fp32 + 16 sums.
    float* Mf = (float*)smem;             // 6 * 16 * 68 floats = 26112 B
    float* Sf = Mf + 6 * 16 * 68;         // 6 * 16 floats
    if (jh != 0) {
        int p = (jh - 1) * 2 + wq;
        #pragma unroll
        for (int ni = 0; ni < 4; ni++)
            #pragma unroll
            for (int r = 0; r < 4; r++)
                Mf[(p * 16 + quad * 4 + r) * 68 + ni * 16 + lr] = accO[ni][r];
        if (lr == 0) {
            #pragma unroll
            for (int r = 0; r < 4; r++)
                Sf[p * 16 + quad * 4 + r] = accS[r];
        }
    }
    __syncthreads();
    if (jh == 0) {
        float inv[4];
        #pragma unroll
        for (int r = 0; r < 4; r++) {
            float t = accS[r];
            #pragma unroll
            for (int jj = 0; jj < 3; jj++) t += Sf[(jj * 2 + wq) * 16 + quad * 4 + r];
            inv[r] = 1.0f / t;
        }
        #pragma unroll
        for (int ni = 0; ni < 4; ni++)
            #pragma unroll
            for (int r = 0; r < 4; r++) {
                float o = accO[ni][r];
                #pragma unroll
                for (int jj = 0; jj < 3; jj++)
                    o += Mf[((jj * 2 + wq) * 16 + quad * 4 + r) * 68 + ni * 16 + lr];
                int row = wq * 16 + quad * 4 + r;
                AO[((size_t)(b * 512 + i0 + row)) * 1024 + h * 64 + ni * 16 + lr] =
                    (half_t)(o * inv[r]);
            }
    }
}

// ---------------------------------------------------------------------------
extern "C" void kernel_launch(void* const* d_in, const int* in_sizes, int n_in,
                              void* d_out, int out_size, void* d_ws, size_t ws_size,
                              hipStream_t stream)
{
    const float* q       = (const float*)d_in[0];
    const float* k       = (const float*)d_in[1];
    const float* v       = (const float*)d_in[2];
    const float* cache_k = (const float*)d_in[3];
    const float* cache_v = (const float*)d_in[4];
    const float* Wq      = (const float*)d_in[5];
    const float* Wk      = (const float*)d_in[6];
    const float* Wv      = (const float*)d_in[7];
    const float* Wo      = (const float*)d_in[8];
    const float* emb_t   = (const float*)d_in[9];
    const float* emb_f   = (const float*)d_in[10];

    float* out   = (float*)d_out;                 // (2,512,1024)
    float* out_k = out + 1048576;                 // (32,64,1536)
    float* out_v = out_k + 3145728;               // (32,1536,64)

    half_t* ws = (half_t*)d_ws;
    half_t* qs_h = ws;                  // 1048576
    half_t* kp_h = ws + 1048576;        //  262144
    half_t* vpT  = ws + 1310720;        //  262144
    half_t* Kc   = ws + 1572864;        // 3145728
    half_t* VcT  = ws + 4718592;        // 3145728
    half_t* WqT  = ws + 7864320;        // 1048576
    half_t* WkvT = ws + 8912896;        //  524288
    half_t* WoT  = ws + 9437184;        // 1048576
    half_t* embc = ws + 10485760;       //   20480
    half_t* AO   = ws + 10506240;       // 1048576

    prep<<<dim3(24, 32, 3), 256, 0, stream>>>(cache_k, cache_v, Wq, Wk, Wv, Wo,
                                              emb_t, emb_f, Kc, VcT, out_k, out_v,
                                              WqT, WkvT, WoT, embc);
    proj<<<dim3(384), 512, 0, stream>>>(0, q, k, v, nullptr, WqT, WkvT, WoT,
                                        qs_h, kp_h, vpT, out, out_k, out_v);
    flash<<<dim3(32, 16), 512, 0, stream>>>(qs_h, Kc, kp_h, VcT, vpT, embc, AO);
    proj<<<dim3(256), 512, 0, stream>>>(1, q, k, v, AO, WqT, WkvT, WoT,
                                        qs_h, kp_h, vpT, out, out_k, out_v);
}